// Round 2
// baseline (2515.742 us; speedup 1.0000x reference)
//
#include <hip/hip_runtime.h>
#include <math.h>

#define H 512
#define V 32000
#define NVB 125     // vocab blocks (32000 / 256)

typedef __attribute__((ext_vector_type(8))) short short8;
typedef __attribute__((ext_vector_type(16))) float float16;

// ---- bf16 split helpers (bit-level RNE, no header-struct dependence) ----
__device__ inline unsigned short f2bf(float x) {
    unsigned int u; __builtin_memcpy(&u, &x, 4);
    unsigned int r = (u + 0x7fffu + ((u >> 16) & 1u)) >> 16;
    return (unsigned short)r;
}
__device__ inline float bfu2f(unsigned short h) {
    unsigned int u = ((unsigned int)h) << 16;
    float f; __builtin_memcpy(&f, &u, 4);
    return f;
}
__device__ inline unsigned int pack_hi2(float x0, float x1,
                                        unsigned short& h0, unsigned short& h1) {
    h0 = f2bf(x0); h1 = f2bf(x1);
    return (unsigned int)h0 | ((unsigned int)h1 << 16);
}

__device__ inline void t2_insert(float& m1, int& c1, float& m2, int& c2,
                                 float v, int idx) {
    if (v > m1 || (v == m1 && idx < c1)) { m2 = m1; c2 = c1; m1 = v; c1 = idx; }
    else if (v > m2 || (v == m2 && idx < c2)) { m2 = v; c2 = idx; }
}

// ---------------------------------------------------------------------------
// Kernel 1: ts = tanh(A @ W_em + b_em), A = [y_hidden (2048x512); y_null (1x512)]
// ---------------------------------------------------------------------------
__global__ __launch_bounds__(256) void k_emstate(
    const float* __restrict__ y_hidden, const float* __restrict__ y_null,
    const float* __restrict__ W, const float* __restrict__ bias,
    float* __restrict__ ts)
{
    const int NR = 2049;
    __shared__ float As[16][64];
    __shared__ float Bs[16][64];
    int rb = blockIdx.y, cb = blockIdx.x;
    int row0 = rb * 64, col0 = cb * 64;
    int tid = threadIdx.x;
    int tr = tid >> 4, tc = tid & 15;
    float acc[4][4] = {};
    for (int k0 = 0; k0 < H; k0 += 16) {
        {
            int r = tid >> 2;
            int kk = (tid & 3) << 2;
            int row = row0 + r;
            float4 v = make_float4(0.f, 0.f, 0.f, 0.f);
            if (row < 2048)       v = *(const float4*)&y_hidden[row * H + k0 + kk];
            else if (row == 2048) v = *(const float4*)&y_null[k0 + kk];
            As[kk + 0][r] = v.x; As[kk + 1][r] = v.y;
            As[kk + 2][r] = v.z; As[kk + 3][r] = v.w;
            int bk = tid >> 4, bc = (tid & 15) << 2;
            *(float4*)&Bs[bk][bc] = *(const float4*)&W[(k0 + bk) * H + col0 + bc];
        }
        __syncthreads();
#pragma unroll
        for (int kk = 0; kk < 16; ++kk) {
            float4 a = *(float4*)&As[kk][tr * 4];
            float4 b = *(float4*)&Bs[kk][tc * 4];
            float av[4] = {a.x, a.y, a.z, a.w};
            float bv[4] = {b.x, b.y, b.z, b.w};
#pragma unroll
            for (int i = 0; i < 4; i++)
#pragma unroll
                for (int j = 0; j < 4; j++) acc[i][j] += av[i] * bv[j];
        }
        __syncthreads();
    }
#pragma unroll
    for (int i = 0; i < 4; i++) {
        int row = row0 + tr * 4 + i;
        if (row >= NR) break;
#pragma unroll
        for (int j = 0; j < 4; j++) {
            int col = col0 + tc * 4 + j;
            ts[row * H + col] = tanhf(acc[i][j] + bias[col]);
        }
    }
}

// ---------------------------------------------------------------------------
// Kernel 2: split-bf16 MFMA logits GEMM + shift-free softmax partials.
// Tile 128 rows x 256 cols, K=512, BK=16, mfma_f32_32x32x16_bf16.
// A*B ~= Ah*Bh + Ah*Bl + Al*Bh  (2-term bf16 split, ~1e-6 logit error).
// Outputs per (row, vocab-block): sum(exp(logit)) and (if TOP2) top-2.
// ---------------------------------------------------------------------------
template<bool TOP2>
__global__ __launch_bounds__(256, 2) void k_gemm_split(
    const float* __restrict__ A, int nrows,
    const float* __restrict__ W, const float* __restrict__ bias,
    float* __restrict__ pL,
    float* __restrict__ pM1, float* __restrict__ pM2,
    int* __restrict__ pI1, int* __restrict__ pI2)
{
    __shared__ __attribute__((aligned(16))) unsigned int AhU[128][8];
    __shared__ __attribute__((aligned(16))) unsigned int AlU[128][8];
    __shared__ __attribute__((aligned(16))) unsigned int BhU[256][8];
    __shared__ __attribute__((aligned(16))) unsigned int BlU[256][8];
    __shared__ float sc_s[128][2];
    __shared__ float sc_m1[128][2], sc_m2[128][2];
    __shared__ int   sc_c1[128][2], sc_c2[128][2];

    const int tid = threadIdx.x;
    const int vb = blockIdx.x, rb = blockIdx.y;
    const int row0 = rb * 128, col0 = vb * 256;
    const int lane = tid & 63, w = tid >> 6;
    const int half = lane >> 5, l31 = lane & 31;
    const int cwBase = (w & 1) * 128;   // this wave's col offset in tile
    const int rwBase = (w >> 1) * 64;   // this wave's row offset in tile

    float16 acc[2][4];
#pragma unroll
    for (int r = 0; r < 2; ++r)
#pragma unroll
        for (int c = 0; c < 4; ++c)
#pragma unroll
            for (int i = 0; i < 16; ++i) acc[r][c][i] = 0.f;

    const int sa_m = tid >> 1, sa_h = tid & 1;   // A staging: row, k-half
    const int sb_n = tid;                        // B staging: col

    auto loadChunk = [&](int c, float (&bv)[16], float (&av)[8]) {
        int k0 = c << 4;
        const float* wp = &W[(size_t)k0 * V + col0 + sb_n];
#pragma unroll
        for (int j = 0; j < 16; ++j) bv[j] = wp[(size_t)j * V];
        int arow = row0 + sa_m;
        if (arow < nrows) {
            const float* ap = &A[(size_t)arow * H + k0 + sa_h * 8];
#pragma unroll
            for (int j = 0; j < 8; ++j) av[j] = ap[j];
        } else {
#pragma unroll
            for (int j = 0; j < 8; ++j) av[j] = 0.f;
        }
    };

    auto writeLDS = [&](float (&bv)[16], float (&av)[8]) {
        unsigned int bh[8], bl[8];
#pragma unroll
        for (int p = 0; p < 8; ++p) {
            unsigned short h0, h1;
            bh[p] = pack_hi2(bv[2 * p], bv[2 * p + 1], h0, h1);
            float r0 = bv[2 * p] - bfu2f(h0);
            float r1 = bv[2 * p + 1] - bfu2f(h1);
            bl[p] = (unsigned int)f2bf(r0) | ((unsigned int)f2bf(r1) << 16);
        }
        *(uint4*)&BhU[sb_n][0] = make_uint4(bh[0], bh[1], bh[2], bh[3]);
        *(uint4*)&BhU[sb_n][4] = make_uint4(bh[4], bh[5], bh[6], bh[7]);
        *(uint4*)&BlU[sb_n][0] = make_uint4(bl[0], bl[1], bl[2], bl[3]);
        *(uint4*)&BlU[sb_n][4] = make_uint4(bl[4], bl[5], bl[6], bl[7]);
        unsigned int ah[4], al[4];
#pragma unroll
        for (int p = 0; p < 4; ++p) {
            unsigned short h0, h1;
            ah[p] = pack_hi2(av[2 * p], av[2 * p + 1], h0, h1);
            float r0 = av[2 * p] - bfu2f(h0);
            float r1 = av[2 * p + 1] - bfu2f(h1);
            al[p] = (unsigned int)f2bf(r0) | ((unsigned int)f2bf(r1) << 16);
        }
        *(uint4*)&AhU[sa_m][sa_h * 4] = make_uint4(ah[0], ah[1], ah[2], ah[3]);
        *(uint4*)&AlU[sa_m][sa_h * 4] = make_uint4(al[0], al[1], al[2], al[3]);
    };

    auto compute = [&]() {
        short8 ah[2], al[2], bh[4], bl[4];
#pragma unroll
        for (int r = 0; r < 2; ++r) {
            int m = rwBase + 32 * r + l31;
            ah[r] = *(const short8*)&AhU[m][half * 4];
            al[r] = *(const short8*)&AlU[m][half * 4];
        }
#pragma unroll
        for (int c = 0; c < 4; ++c) {
            int n = cwBase + 32 * c + l31;
            bh[c] = *(const short8*)&BhU[n][half * 4];
            bl[c] = *(const short8*)&BlU[n][half * 4];
        }
#pragma unroll
        for (int r = 0; r < 2; ++r)
#pragma unroll
            for (int c = 0; c < 4; ++c) {
                acc[r][c] = __builtin_amdgcn_mfma_f32_32x32x16_bf16(ah[r], bh[c], acc[r][c], 0, 0, 0);
                acc[r][c] = __builtin_amdgcn_mfma_f32_32x32x16_bf16(ah[r], bl[c], acc[r][c], 0, 0, 0);
                acc[r][c] = __builtin_amdgcn_mfma_f32_32x32x16_bf16(al[r], bh[c], acc[r][c], 0, 0, 0);
            }
    };

    float bv0[16], av0[8], bv1[16], av1[8];
    loadChunk(0, bv0, av0);
    for (int cc = 0; cc < 16; ++cc) {
        __syncthreads();
        writeLDS(bv0, av0);
        __syncthreads();
        loadChunk(2 * cc + 1, bv1, av1);   // prefetch under MFMA
        compute();
        __syncthreads();
        writeLDS(bv1, av1);
        __syncthreads();
        if (cc < 15) loadChunk(2 * cc + 2, bv0, av0);
        compute();
    }

    // ---- epilogue: shift-free sumexp (+ top-2) per row over this 256-col block
    float biasv[4];
#pragma unroll
    for (int c = 0; c < 4; ++c) biasv[c] = bias[col0 + cwBase + 32 * c + l31];

#pragma unroll
    for (int r = 0; r < 2; ++r) {
#pragma unroll
        for (int i = 0; i < 16; ++i) {
            float v0 = acc[r][0][i] + biasv[0];
            float v1 = acc[r][1][i] + biasv[1];
            float v2 = acc[r][2][i] + biasv[2];
            float v3 = acc[r][3][i] + biasv[3];
            float s = __expf(v0) + __expf(v1) + __expf(v2) + __expf(v3);
            float m1 = 0.f, m2 = 0.f; int c1 = 0, c2 = 0;
            if (TOP2) {
                int g0 = col0 + cwBase + l31;
                m1 = v0; c1 = g0; m2 = -1e30f; c2 = 0x7fffffff;
                t2_insert(m1, c1, m2, c2, v1, g0 + 32);
                t2_insert(m1, c1, m2, c2, v2, g0 + 64);
                t2_insert(m1, c1, m2, c2, v3, g0 + 96);
            }
            for (int st = 1; st < 32; st <<= 1) {
                s += __shfl_xor(s, st, 64);
                if (TOP2) {
                    float om1 = __shfl_xor(m1, st, 64); int oc1 = __shfl_xor(c1, st, 64);
                    float om2 = __shfl_xor(m2, st, 64); int oc2 = __shfl_xor(c2, st, 64);
                    t2_insert(m1, c1, m2, c2, om1, oc1);
                    t2_insert(m1, c1, m2, c2, om2, oc2);
                }
            }
            int rowLoc = rwBase + 32 * r + (i & 3) + 8 * (i >> 2) + 4 * half;
            if (l31 == 0) {
                sc_s[rowLoc][w & 1] = s;
                if (TOP2) {
                    sc_m1[rowLoc][w & 1] = m1; sc_c1[rowLoc][w & 1] = c1;
                    sc_m2[rowLoc][w & 1] = m2; sc_c2[rowLoc][w & 1] = c2;
                }
            }
        }
    }
    __syncthreads();
    if (tid < 128) {
        int rowG = row0 + tid;
        float s = sc_s[tid][0] + sc_s[tid][1];
        pL[(size_t)rowG * NVB + vb] = s;
        if (TOP2) {
            float m1 = sc_m1[tid][0]; int c1 = sc_c1[tid][0];
            float m2 = sc_m2[tid][0]; int c2 = sc_c2[tid][0];
            t2_insert(m1, c1, m2, c2, sc_m1[tid][1], sc_c1[tid][1]);
            t2_insert(m1, c1, m2, c2, sc_m2[tid][1], sc_c2[tid][1]);
            pM1[(size_t)rowG * NVB + vb] = m1;
            pM2[(size_t)rowG * NVB + vb] = m2;
            pI1[(size_t)rowG * NVB + vb] = c1;
            pI2[(size_t)rowG * NVB + vb] = c2;
        }
    }
}

// ---------------------------------------------------------------------------
// Kernel 3a: combine source partials -> L0 (denominator only)
// ---------------------------------------------------------------------------
__global__ __launch_bounds__(256) void k_combine_src(
    const float* __restrict__ pL, int nrows, float* __restrict__ L)
{
    int w = threadIdx.x >> 6, ll = threadIdx.x & 63;
    int row = blockIdx.x * 4 + w;
    if (row >= nrows) return;
    const float* p = &pL[(size_t)row * NVB];
    float s = (ll < NVB ? p[ll] : 0.f) + (ll + 64 < NVB ? p[ll + 64] : 0.f);
    for (int st = 1; st < 64; st <<= 1) s += __shfl_xor(s, st, 64);
    if (ll == 0) L[row] = s;
}

// ---------------------------------------------------------------------------
// Kernel 3b: combine target partials -> L1 + global approx top-2 candidates
// ---------------------------------------------------------------------------
__global__ __launch_bounds__(256) void k_combine_tgt(
    const float* __restrict__ pL,
    const float* __restrict__ pM1, const float* __restrict__ pM2,
    const int* __restrict__ pI1, const int* __restrict__ pI2,
    float* __restrict__ L, int* __restrict__ C0, int* __restrict__ C1)
{
    int w = threadIdx.x >> 6, ll = threadIdx.x & 63;
    int row = blockIdx.x * 4 + w;
    if (row >= 2048) return;
    size_t base = (size_t)row * NVB;
    float s = 0.f;
    float m1 = -1e30f, m2 = -1e30f; int c1 = 0x7fffffff, c2 = 0x7fffffff;
    for (int vb = ll; vb < NVB; vb += 64) {
        s += pL[base + vb];
        t2_insert(m1, c1, m2, c2, pM1[base + vb], pI1[base + vb]);
        t2_insert(m1, c1, m2, c2, pM2[base + vb], pI2[base + vb]);
    }
    for (int st = 1; st < 64; st <<= 1) {
        s += __shfl_xor(s, st, 64);
        float om1 = __shfl_xor(m1, st, 64); int oc1 = __shfl_xor(c1, st, 64);
        float om2 = __shfl_xor(m2, st, 64); int oc2 = __shfl_xor(c2, st, 64);
        t2_insert(m1, c1, m2, c2, om1, oc1);
        t2_insert(m1, c1, m2, c2, om2, oc2);
    }
    if (ll == 0) { L[row] = s; C0[row] = c1; C1[row] = c2; }
}

// ---------------------------------------------------------------------------
// Kernel 4: emission output (exact f32 dot for gathered columns)
// ---------------------------------------------------------------------------
__global__ __launch_bounds__(256) void k_emission(
    const float* __restrict__ ts, const float* __restrict__ W_sv,
    const float* __restrict__ b_sv, const int* __restrict__ sources,
    const float* __restrict__ L, float* __restrict__ out)
{
    __shared__ float wcol[H];
    __shared__ float sbias;
    int b = blockIdx.y, tx = blockIdx.x;
    int tid = threadIdx.x;
    int s = sources[b * 64 + tx];
    wcol[tid]       = W_sv[(size_t)tid * V + s];
    wcol[tid + 256] = W_sv[(size_t)(tid + 256) * V + s];
    if (tid == 0) sbias = b_sv[s];
    __syncthreads();
    int w = tid >> 6, ll = tid & 63;
    for (int r = w; r <= 64; r += 4) {
        int row = (r < 64) ? (b * 64 + r) : 2048;
        const float* a = &ts[(size_t)row * H];
        float sum = 0.f;
#pragma unroll
        for (int j = 0; j < 8; ++j) sum += a[ll * 8 + j] * wcol[ll * 8 + j];
        for (int m2 = 1; m2 < 64; m2 <<= 1) sum += __shfl_xor(sum, m2, 64);
        float prob = __expf(sum + sbias) / L[row];
        if (r < 64) {
            if (ll == 0) out[b * 8192 + r * 64 + tx] = prob;
        } else {
            out[b * 8192 + (64 + ll) * 64 + tx] = prob;
        }
    }
}

// ---------------------------------------------------------------------------
// Kernel 5: target epilogue — exact recompute of token + 2 argmax candidates
// ---------------------------------------------------------------------------
__global__ __launch_bounds__(256) void k_target_final(
    const float* __restrict__ tstate,
    const float* __restrict__ W_tv, const float* __restrict__ b_tv,
    const int* __restrict__ targets, const int* __restrict__ tlen,
    const float* __restrict__ L, const int* __restrict__ C0,
    const int* __restrict__ C1,
    float* __restrict__ out_exp, float* __restrict__ out_log,
    float* __restrict__ out_pred)
{
    int w = threadIdx.x >> 6, ll = threadIdx.x & 63;
    int row = blockIdx.x * 4 + w;
    if (row >= 2048) return;
    int tok = targets[row], a0 = C0[row], a1 = C1[row];
    const float* a = &tstate[(size_t)row * H];
    float s0 = 0.f, s1 = 0.f, s2 = 0.f;
#pragma unroll
    for (int j = 0; j < 8; ++j) {
        int k = ll * 8 + j;
        float av = a[k];
        const float* wr = &W_tv[(size_t)k * V];
        s0 += av * wr[tok]; s1 += av * wr[a0]; s2 += av * wr[a1];
    }
    for (int st = 1; st < 64; st <<= 1) {
        s0 += __shfl_xor(s0, st, 64);
        s1 += __shfl_xor(s1, st, 64);
        s2 += __shfl_xor(s2, st, 64);
    }
    if (ll == 0) {
        float ltok = s0 + b_tv[tok];
        float v0 = s1 + b_tv[a0], v1 = s2 + b_tv[a1];
        int pred = (v1 > v0 || (v1 == v0 && a1 < a0)) ? a1 : a0;
        float Li = L[row];
        int bb = row >> 6, t = row & 63;
        int mask = (t < tlen[bb]) ? 1 : 0;
        float prob = __expf(ltok) / Li;
        out_exp[row]  = mask ? prob : 0.f;
        out_log[row]  = mask ? (ltok - __logf(Li)) : 0.f;
        out_pred[row] = (float)pred;
    }
}

// ---------------------------------------------------------------------------
extern "C" void kernel_launch(void* const* d_in, const int* in_sizes, int n_in,
                              void* d_out, int out_size, void* d_ws, size_t ws_size,
                              hipStream_t stream)
{
    const float* y_hidden = (const float*)d_in[0];
    const float* y_null   = (const float*)d_in[1];
    const float* tstate   = (const float*)d_in[2];
    const float* W_em     = (const float*)d_in[3];
    const float* b_em     = (const float*)d_in[4];
    const float* W_sv     = (const float*)d_in[5];
    const float* b_sv     = (const float*)d_in[6];
    const float* W_tv     = (const float*)d_in[7];
    const float* b_tv     = (const float*)d_in[8];
    const int*   sources  = (const int*)d_in[9];
    const int*   targets  = (const int*)d_in[10];
    const int*   tlen     = (const int*)d_in[11];

    float* out = (float*)d_out;
    float* out_em   = out;
    float* out_exp  = out + 262144;
    float* out_log  = out + 264192;
    float* out_pred = out + 266240;

    float* ws = (float*)d_ws;
    size_t off = 0;
    float* ts   = ws + off; off += 2049 * H;        // 2049x512
    float* pL0  = ws + off; off += 2176 * NVB;      // padded to 17*128 rows
    float* pL1  = ws + off; off += 2048 * NVB;
    float* pM1a = ws + off; off += 2048 * NVB;
    float* pM1b = ws + off; off += 2048 * NVB;
    int*   pI1a = (int*)(ws + off); off += 2048 * NVB;
    int*   pI1b = (int*)(ws + off); off += 2048 * NVB;
    float* L0   = ws + off; off += 2176;
    float* L1   = ws + off; off += 2048;
    int*   C0   = (int*)(ws + off); off += 2048;
    int*   C1   = (int*)(ws + off); off += 2048;

    // 1) hidden-state transform
    k_emstate<<<dim3(8, 33), 256, 0, stream>>>(y_hidden, y_null, W_em, b_em, ts);

    // 2) split-bf16 MFMA logits GEMMs + softmax partials
    k_gemm_split<false><<<dim3(NVB, 17), 256, 0, stream>>>(
        ts, 2049, W_sv, b_sv, pL0, nullptr, nullptr, nullptr, nullptr);
    k_gemm_split<true><<<dim3(NVB, 16), 256, 0, stream>>>(
        tstate, 2048, W_tv, b_tv, pL1, pM1a, pM1b, pI1a, pI1b);

    // 3) combine partials
    k_combine_src<<<(2049 + 3) / 4, 256, 0, stream>>>(pL0, 2049, L0);
    k_combine_tgt<<<2048 / 4, 256, 0, stream>>>(pL1, pM1a, pM1b, pI1a, pI1b,
                                                L1, C0, C1);

    // 4) emission gather (exact f32 logits)
    k_emission<<<dim3(64, 32), 256, 0, stream>>>(ts, W_sv, b_sv, sources, L0, out_em);

    // 5) target epilogue with exact candidate recompute
    k_target_final<<<2048 / 4, 256, 0, stream>>>(tstate, W_tv, b_tv, targets, tlen,
                                                 L1, C0, C1,
                                                 out_exp, out_log, out_pred);
}